// Round 7
// baseline (826.264 us; speedup 1.0000x reference)
//
#include <hip/hip_runtime.h>

#define N_NODES 500000
#define N_EDGES 5000000
#define N_GRAPHS 5000
#define FEAT 7
#define STATE 16
#define NBUCK ((N_NODES + 1023) >> 10)   // 489 buckets of 1024 nodes
#define NBLK1 512
#define EPB ((N_EDGES + NBLK1 - 1) / NBLK1)  // 9766 edges per pass-1 block

__device__ __forceinline__ float4 f4add(float4 a, float4 b) {
    return make_float4(a.x + b.x, a.y + b.y, a.z + b.z, a.w + b.w);
}
__device__ __forceinline__ float4 f4fma(float s, float4 a, float4 b) {
    return make_float4(fmaf(s, a.x, b.x), fmaf(s, a.y, b.y),
                       fmaf(s, a.z, b.z), fmaf(s, a.w, b.w));
}
__device__ __forceinline__ float4 f4relu(float4 a) {
    return make_float4(fmaxf(a.x, 0.f), fmaxf(a.y, 0.f),
                       fmaxf(a.z, 0.f), fmaxf(a.w, 0.f));
}
__device__ __forceinline__ float4 f4shflxor(float4 a, int m) {
    return make_float4(__shfl_xor(a.x, m), __shfl_xor(a.y, m),
                       __shfl_xor(a.z, m), __shfl_xor(a.w, m));
}

// ---------------- zero an int buffer ----------------------------------------
__global__ __launch_bounds__(256) void k_zero(int* __restrict__ p, int n) {
    int i = blockIdx.x * 256 + threadIdx.x;
    if (i < n) p[i] = 0;
}

// ------ input layer + round-0 message, fused --------------------------------
// state = relu(x @ in_W + in_b);  message = relu(state @ mW + mb)
__global__ __launch_bounds__(256) void k_input(const float* __restrict__ x,
                                               const float* __restrict__ W,
                                               const float* __restrict__ b,
                                               const float* __restrict__ mW,
                                               const float* __restrict__ mb,
                                               float* __restrict__ state,
                                               float* __restrict__ message) {
    int i = blockIdx.x * 256 + threadIdx.x;
    if (i >= N_NODES) return;
    float xi[FEAT];
#pragma unroll
    for (int f = 0; f < FEAT; ++f) xi[f] = x[(size_t)i * FEAT + f];
    float o[STATE];
#pragma unroll
    for (int s = 0; s < STATE; ++s) {
        float acc = b[s];
#pragma unroll
        for (int f = 0; f < FEAT; ++f) acc = fmaf(xi[f], W[f * STATE + s], acc);
        o[s] = fmaxf(acc, 0.f);
    }
    float4* dst = reinterpret_cast<float4*>(state + (size_t)i * STATE);
#pragma unroll
    for (int q = 0; q < 4; ++q)
        dst[q] = make_float4(o[4 * q], o[4 * q + 1], o[4 * q + 2], o[4 * q + 3]);
    float mo[STATE];
#pragma unroll
    for (int s = 0; s < STATE; ++s) {
        float acc = mb[s];
#pragma unroll
        for (int k = 0; k < STATE; ++k) acc = fmaf(o[k], mW[k * STATE + s], acc);
        mo[s] = fmaxf(acc, 0.f);
    }
    float4* mp = reinterpret_cast<float4*>(message + (size_t)i * STATE);
#pragma unroll
    for (int q = 0; q < 4; ++q)
        mp[q] = make_float4(mo[4 * q], mo[4 * q + 1], mo[4 * q + 2], mo[4 * q + 3]);
}

// ---- CSR pass 1a: per-block bucket histogram + global base capture ---------
__global__ __launch_bounds__(256) void k_bhist(const int* __restrict__ ei,
                                               int* __restrict__ bcnt,
                                               int* __restrict__ bb) {
    __shared__ int bins[NBUCK];
    int t = threadIdx.x, blk = blockIdx.x;
    for (int k = t; k < NBUCK; k += 256) bins[k] = 0;
    __syncthreads();
    int e0 = blk * EPB, e1 = min(e0 + EPB, N_EDGES);
    for (int e = e0 + t; e < e1; e += 256) {
        int d = ei[N_EDGES + e];
        atomicAdd(&bins[d >> 10], 1);
    }
    __syncthreads();
    for (int k = t; k < NBUCK; k += 256)
        bb[blk * NBUCK + k] = atomicAdd(&bcnt[k], bins[k]);
}

// ---- CSR pass 1b: tiny exclusive scan of bucket counts ---------------------
__global__ __launch_bounds__(256) void k_bscan(const int* __restrict__ bcnt,
                                               int* __restrict__ boffs,
                                               int* __restrict__ offs) {
    __shared__ int sc[NBUCK];
    int t = threadIdx.x;
    for (int k = t; k < NBUCK; k += 256) sc[k] = bcnt[k];
    __syncthreads();
    if (t == 0) {
        int run = 0;
        for (int k = 0; k < NBUCK; ++k) { int v = sc[k]; sc[k] = run; run += v; }
    }
    __syncthreads();
    for (int k = t; k < NBUCK; k += 256) boffs[k] = sc[k];
    if (t == 0) { boffs[NBUCK] = N_EDGES; offs[N_NODES] = N_EDGES; }
}

// ---- CSR pass 1c: partition edges into bucket-contiguous packed storage ----
// pack = src | (dst&1023)<<19   (valid: N_NODES < 2^19)
__global__ __launch_bounds__(256) void k_bscatter(const int* __restrict__ ei,
                                                  const int* __restrict__ boffs,
                                                  const int* __restrict__ bb,
                                                  int* __restrict__ ebuf) {
    __shared__ int cur[NBUCK];
    int t = threadIdx.x, blk = blockIdx.x;
    for (int k = t; k < NBUCK; k += 256) cur[k] = 0;
    __syncthreads();
    int e0 = blk * EPB, e1 = min(e0 + EPB, N_EDGES);
    for (int e = e0 + t; e < e1; e += 256) {
        int s = ei[e];
        int d = ei[N_EDGES + e];
        int bin = d >> 10;
        int r = atomicAdd(&cur[bin], 1);
        ebuf[boffs[bin] + bb[blk * NBUCK + bin] + r] = s | ((d & 1023) << 19);
    }
}

// ---- CSR pass 2: per-bucket CSR build fully in LDS (no global atomics) -----
__global__ __launch_bounds__(256) void k_bcsr(const int* __restrict__ ebuf,
                                              const int* __restrict__ boffs,
                                              int* __restrict__ offs,
                                              int* __restrict__ srcs) {
    __shared__ int hist[1024];
    __shared__ int cur[1024];
    __shared__ int wsum[4];
    int t = threadIdx.x, blk = blockIdx.x;
    int nb = blk << 10;
    int nn = min(1024, N_NODES - nb);
    for (int k = t; k < 1024; k += 256) hist[k] = 0;
    __syncthreads();
    int e0 = boffs[blk], e1 = boffs[blk + 1];
    for (int e = e0 + t; e < e1; e += 256)
        atomicAdd(&hist[(ebuf[e] >> 19) & 1023], 1);
    __syncthreads();
    int v0 = hist[4 * t], v1 = hist[4 * t + 1], v2 = hist[4 * t + 2], v3 = hist[4 * t + 3];
    int tsum = v0 + v1 + v2 + v3;
    int lane = t & 63, w = t >> 6;
    int s = tsum;
#pragma unroll
    for (int off = 1; off < 64; off <<= 1) {
        int o = __shfl_up(s, off);
        if (lane >= off) s += o;
    }
    if (lane == 63) wsum[w] = s;
    __syncthreads();
    int wofs = 0;
#pragma unroll
    for (int k = 0; k < 4; ++k)
        if (k < w) wofs += wsum[k];
    int ex = wofs + s - tsum;
    cur[4 * t] = ex;
    cur[4 * t + 1] = ex + v0;
    cur[4 * t + 2] = ex + v0 + v1;
    cur[4 * t + 3] = ex + v0 + v1 + v2;
    __syncthreads();
    for (int k = t; k < nn; k += 256) offs[nb + k] = e0 + cur[k];
    __syncthreads();  // offs reads of cur[] must precede cursor atomics
    for (int e = e0 + t; e < e1; e += 256) {
        int p = ebuf[e];
        int r = atomicAdd(&cur[(p >> 19) & 1023], 1);
        srcs[e0 + r] = p & 0x7FFFF;
    }
}

// ------- message = relu(state @ W + b) --------------------------------------
__global__ __launch_bounds__(256) void k_message(const float* __restrict__ state,
                                                 const float* __restrict__ W,
                                                 const float* __restrict__ b,
                                                 float* __restrict__ message) {
    int i = blockIdx.x * 256 + threadIdx.x;
    if (i >= N_NODES) return;
    const float4* sp = reinterpret_cast<const float4*>(state + (size_t)i * STATE);
    float4 v0 = sp[0], v1 = sp[1], v2 = sp[2], v3 = sp[3];
    float st[STATE] = {v0.x, v0.y, v0.z, v0.w, v1.x, v1.y, v1.z, v1.w,
                       v2.x, v2.y, v2.z, v2.w, v3.x, v3.y, v3.z, v3.w};
    float o[STATE];
#pragma unroll
    for (int s = 0; s < STATE; ++s) {
        float acc = b[s];
#pragma unroll
        for (int k = 0; k < STATE; ++k) acc = fmaf(st[k], W[k * STATE + s], acc);
        o[s] = fmaxf(acc, 0.f);
    }
    float4* mp = reinterpret_cast<float4*>(message + (size_t)i * STATE);
#pragma unroll
    for (int q = 0; q < 4; ++q)
        mp[q] = make_float4(o[4 * q], o[4 * q + 1], o[4 * q + 2], o[4 * q + 3]);
}

// ------- gather + fused update, 4 lanes per node ----------------------------
// lane q of a quad reads float4 #q of each gathered message row (coalesced
// 64B line per quad), accumulates 4 channels; 16x16 matmul done as per-lane
// partial (its 4 k's x all 16 s) + quad shfl_xor reduction.
__global__ __launch_bounds__(256) void k_gather_update(
    const float* __restrict__ message, const int* __restrict__ offs,
    const int* __restrict__ srcs, const float* __restrict__ W,
    const float* __restrict__ b, float* __restrict__ state) {
    int t = blockIdx.x * 256 + threadIdx.x;
    int node = t >> 2, q = t & 3;
    if (node >= N_NODES) return;
    int start = offs[node], end = offs[node + 1];
    const float4* mv = reinterpret_cast<const float4*>(message);
    float4 acc = make_float4(0.f, 0.f, 0.f, 0.f);
    int j = start;
    for (; j + 2 <= end; j += 2) {
        int s0 = srcs[j], s1 = srcs[j + 1];
        float4 m0 = mv[4 * (size_t)s0 + q];
        float4 m1 = mv[4 * (size_t)s1 + q];
        acc = f4add(acc, m0);
        acc = f4add(acc, m1);
    }
    if (j < end) acc = f4add(acc, mv[4 * (size_t)srcs[j] + q]);
    // partial matmul: channels k = 4q+m, all 16 outputs (as 4 float4s)
    const float4* Wv = reinterpret_cast<const float4*>(W);
    float4 p0 = make_float4(0.f, 0.f, 0.f, 0.f), p1 = p0, p2 = p0, p3 = p0;
#pragma unroll
    for (int m = 0; m < 4; ++m) {
        float a = (m == 0) ? acc.x : (m == 1) ? acc.y : (m == 2) ? acc.z : acc.w;
        const float4* wr = Wv + (size_t)(4 * q + m) * 4;
        p0 = f4fma(a, wr[0], p0);
        p1 = f4fma(a, wr[1], p1);
        p2 = f4fma(a, wr[2], p2);
        p3 = f4fma(a, wr[3], p3);
    }
    // quad reduction over k-blocks
    p0 = f4add(p0, f4shflxor(p0, 1));  p1 = f4add(p1, f4shflxor(p1, 1));
    p2 = f4add(p2, f4shflxor(p2, 1));  p3 = f4add(p3, f4shflxor(p3, 1));
    p0 = f4add(p0, f4shflxor(p0, 2));  p1 = f4add(p1, f4shflxor(p1, 2));
    p2 = f4add(p2, f4shflxor(p2, 2));  p3 = f4add(p3, f4shflxor(p3, 2));
    // bias + relu (all lanes hold full 16-vector)
    const float4* bv = reinterpret_cast<const float4*>(b);
    float4 o0 = f4relu(f4add(p0, bv[0]));
    float4 o1 = f4relu(f4add(p1, bv[1]));
    float4 o2 = f4relu(f4add(p2, bv[2]));
    float4 o3 = f4relu(f4add(p3, bv[3]));
    // select this lane's quad block and update its float4 of the state row
    float4 e01 = (q & 1) ? o1 : o0;
    float4 e23 = (q & 1) ? o3 : o2;
    float4 r   = (q & 2) ? e23 : e01;
    float4* spv = reinterpret_cast<float4*>(state + (size_t)node * STATE);
    float4 sv = spv[q];
    spv[q] = f4add(sv, r);
}

// ------------- out[g] = out_b -----------------------------------------------
__global__ __launch_bounds__(256) void k_out_init(const float* __restrict__ out_b,
                                                  float* __restrict__ out) {
    int g = blockIdx.x * 256 + threadIdx.x;
    if (g < N_GRAPHS) out[g] = out_b[0];
}

// ------------- out[batch[i]] += dot(state[i], out_W) ------------------------
__global__ __launch_bounds__(256) void k_reduce(const float* __restrict__ state,
                                                const int* __restrict__ batch,
                                                const float* __restrict__ out_W,
                                                float* __restrict__ out) {
    int i = blockIdx.x * 256 + threadIdx.x;
    int lane = threadIdx.x & 63;
    bool valid = (i < N_NODES);
    float v = 0.f;
    int bg = -1;
    if (valid) {
        bg = batch[i];
        const float4* sp = reinterpret_cast<const float4*>(state + (size_t)i * STATE);
        float4 s0 = sp[0], s1 = sp[1], s2 = sp[2], s3 = sp[3];
        float st[STATE] = {s0.x, s0.y, s0.z, s0.w, s1.x, s1.y, s1.z, s1.w,
                           s2.x, s2.y, s2.z, s2.w, s3.x, s3.y, s3.z, s3.w};
        float acc = 0.f;
#pragma unroll
        for (int k = 0; k < STATE; ++k) acc = fmaf(st[k], out_W[k], acc);
        v = acc;
    }
#pragma unroll
    for (int off = 1; off < 64; off <<= 1) {
        float ov = __shfl_up(v, off);
        int ob = __shfl_up(bg, off);
        if (lane >= off && ob == bg) v += ov;
    }
    int nb = __shfl_down(bg, 1);
    if (valid && (lane == 63 || nb != bg)) unsafeAtomicAdd(&out[bg], v);
}

extern "C" void kernel_launch(void* const* d_in, const int* in_sizes, int n_in,
                              void* d_out, int out_size, void* d_ws, size_t ws_size,
                              hipStream_t stream) {
    const float* x     = (const float*)d_in[0];
    const int*   ei    = (const int*)d_in[1];
    const int*   batch = (const int*)d_in[2];
    const float* in_W  = (const float*)d_in[3];
    const float* in_b  = (const float*)d_in[4];
    const float* msg_W = (const float*)d_in[5];
    const float* msg_b = (const float*)d_in[6];
    const float* upd_W = (const float*)d_in[7];
    const float* upd_b = (const float*)d_in[8];
    const float* out_W = (const float*)d_in[9];
    const float* out_b = (const float*)d_in[10];
    float* out = (float*)d_out;

    // workspace layout (~88 MB):
    float* state   = (float*)d_ws;                               // 32 MB
    float* message = state + (size_t)N_NODES * STATE;            // 32 MB
    int*   srcs    = (int*)(message + (size_t)N_NODES * STATE);  // 20 MB
    int*   offs    = srcs + N_EDGES;                             // 2 MB (+1)
    int*   bcnt    = offs + N_NODES + 1;                         // 489
    int*   boffs   = bcnt + NBUCK;                               // 490
    int*   bb      = boffs + NBUCK + 1;                          // 1 MB
    // ebuf (20 MB) overlaps state: only live during CSR build, before k_input
    int*   ebuf    = (int*)d_ws;

    const int nbN = (N_NODES + 255) / 256;
    const int nbQ = ((N_NODES * 4) + 255) / 256;   // 4 lanes per node
    const int nbG = (N_GRAPHS + 255) / 256;

    // ---- CSR build by dst (bucketed, near-atomic-free) ----
    k_zero<<<(NBUCK + 255) / 256, 256, 0, stream>>>(bcnt, NBUCK);
    k_bhist<<<NBLK1, 256, 0, stream>>>(ei, bcnt, bb);
    k_bscan<<<1, 256, 0, stream>>>(bcnt, boffs, offs);
    k_bscatter<<<NBLK1, 256, 0, stream>>>(ei, boffs, bb, ebuf);
    k_bcsr<<<NBUCK, 256, 0, stream>>>(ebuf, boffs, offs, srcs);

    // ---- GNN ----
    k_input<<<nbN, 256, 0, stream>>>(x, in_W, in_b, msg_W, msg_b, state, message);
    for (int r = 0; r < 4; ++r) {
        k_gather_update<<<nbQ, 256, 0, stream>>>(message, offs, srcs,
                                                 upd_W + r * STATE * STATE,
                                                 upd_b + r * STATE, state);
        if (r < 3)
            k_message<<<nbN, 256, 0, stream>>>(state, msg_W + (r + 1) * STATE * STATE,
                                               msg_b + (r + 1) * STATE, message);
    }
    k_out_init<<<nbG, 256, 0, stream>>>(out_b, out);
    k_reduce<<<nbN, 256, 0, stream>>>(state, batch, out_W, out);
}

// Round 11
// 822.711 us; speedup vs baseline: 1.0043x; 1.0043x over previous
//
#include <hip/hip_runtime.h>

#define N_NODES 500000
#define N_EDGES 5000000
#define N_GRAPHS 5000
#define FEAT 7
#define STATE 16
#define NBUCK ((N_NODES + 1023) >> 10)   // 489 buckets of 1024 nodes
#define NBLK1 512
#define EPB ((N_EDGES + NBLK1 - 1) / NBLK1)  // 9766 edges per pass-1 block

__device__ __forceinline__ float4 f4add(float4 a, float4 b) {
    return make_float4(a.x + b.x, a.y + b.y, a.z + b.z, a.w + b.w);
}

// ---------------- zero an int buffer ----------------------------------------
__global__ __launch_bounds__(256) void k_zero(int* __restrict__ p, int n) {
    int i = blockIdx.x * 256 + threadIdx.x;
    if (i < n) p[i] = 0;
}

// ------ input layer + round-0 message, fused --------------------------------
__global__ __launch_bounds__(256) void k_input(const float* __restrict__ x,
                                               const float* __restrict__ W,
                                               const float* __restrict__ b,
                                               const float* __restrict__ mW,
                                               const float* __restrict__ mb,
                                               float* __restrict__ state,
                                               float* __restrict__ message) {
    int i = blockIdx.x * 256 + threadIdx.x;
    if (i >= N_NODES) return;
    float xi[FEAT];
#pragma unroll
    for (int f = 0; f < FEAT; ++f) xi[f] = x[(size_t)i * FEAT + f];
    float o[STATE];
#pragma unroll
    for (int s = 0; s < STATE; ++s) {
        float acc = b[s];
#pragma unroll
        for (int f = 0; f < FEAT; ++f) acc = fmaf(xi[f], W[f * STATE + s], acc);
        o[s] = fmaxf(acc, 0.f);
    }
    float4* dst = reinterpret_cast<float4*>(state + (size_t)i * STATE);
#pragma unroll
    for (int q = 0; q < 4; ++q)
        dst[q] = make_float4(o[4 * q], o[4 * q + 1], o[4 * q + 2], o[4 * q + 3]);
    float mo[STATE];
#pragma unroll
    for (int s = 0; s < STATE; ++s) {
        float acc = mb[s];
#pragma unroll
        for (int k = 0; k < STATE; ++k) acc = fmaf(o[k], mW[k * STATE + s], acc);
        mo[s] = fmaxf(acc, 0.f);
    }
    float4* mp = reinterpret_cast<float4*>(message + (size_t)i * STATE);
#pragma unroll
    for (int q = 0; q < 4; ++q)
        mp[q] = make_float4(mo[4 * q], mo[4 * q + 1], mo[4 * q + 2], mo[4 * q + 3]);
}

// ---- CSR pass 1a: per-block bucket histogram + global base capture ---------
__global__ __launch_bounds__(256) void k_bhist(const int* __restrict__ ei,
                                               int* __restrict__ bcnt,
                                               int* __restrict__ bb) {
    __shared__ int bins[NBUCK];
    int t = threadIdx.x, blk = blockIdx.x;
    for (int k = t; k < NBUCK; k += 256) bins[k] = 0;
    __syncthreads();
    int e0 = blk * EPB, e1 = min(e0 + EPB, N_EDGES);
    for (int e = e0 + t; e < e1; e += 256) {
        int d = ei[N_EDGES + e];
        atomicAdd(&bins[d >> 10], 1);
    }
    __syncthreads();
    for (int k = t; k < NBUCK; k += 256)
        bb[blk * NBUCK + k] = atomicAdd(&bcnt[k], bins[k]);
}

// ---- CSR pass 1b: tiny exclusive scan of bucket counts ---------------------
__global__ __launch_bounds__(256) void k_bscan(const int* __restrict__ bcnt,
                                               int* __restrict__ boffs,
                                               int* __restrict__ offs) {
    __shared__ int sc[NBUCK];
    int t = threadIdx.x;
    for (int k = t; k < NBUCK; k += 256) sc[k] = bcnt[k];
    __syncthreads();
    if (t == 0) {
        int run = 0;
        for (int k = 0; k < NBUCK; ++k) { int v = sc[k]; sc[k] = run; run += v; }
    }
    __syncthreads();
    for (int k = t; k < NBUCK; k += 256) boffs[k] = sc[k];
    if (t == 0) { boffs[NBUCK] = N_EDGES; offs[N_NODES] = N_EDGES; }
}

// ---- CSR pass 1c: partition edges into bucket-contiguous packed storage ----
// pack = src | (dst&1023)<<19   (valid: N_NODES < 2^19)
__global__ __launch_bounds__(256) void k_bscatter(const int* __restrict__ ei,
                                                  const int* __restrict__ boffs,
                                                  const int* __restrict__ bb,
                                                  int* __restrict__ ebuf) {
    __shared__ int cur[NBUCK];
    int t = threadIdx.x, blk = blockIdx.x;
    for (int k = t; k < NBUCK; k += 256) cur[k] = 0;
    __syncthreads();
    int e0 = blk * EPB, e1 = min(e0 + EPB, N_EDGES);
    for (int e = e0 + t; e < e1; e += 256) {
        int s = ei[e];
        int d = ei[N_EDGES + e];
        int bin = d >> 10;
        int r = atomicAdd(&cur[bin], 1);
        ebuf[boffs[bin] + bb[blk * NBUCK + bin] + r] = s | ((d & 1023) << 19);
    }
}

// ---- CSR pass 2: per-bucket CSR build fully in LDS (no global atomics) -----
__global__ __launch_bounds__(256) void k_bcsr(const int* __restrict__ ebuf,
                                              const int* __restrict__ boffs,
                                              int* __restrict__ offs,
                                              int* __restrict__ srcs) {
    __shared__ int hist[1024];
    __shared__ int cur[1024];
    __shared__ int wsum[4];
    int t = threadIdx.x, blk = blockIdx.x;
    int nb = blk << 10;
    int nn = min(1024, N_NODES - nb);
    for (int k = t; k < 1024; k += 256) hist[k] = 0;
    __syncthreads();
    int e0 = boffs[blk], e1 = boffs[blk + 1];
    for (int e = e0 + t; e < e1; e += 256)
        atomicAdd(&hist[(ebuf[e] >> 19) & 1023], 1);
    __syncthreads();
    int v0 = hist[4 * t], v1 = hist[4 * t + 1], v2 = hist[4 * t + 2], v3 = hist[4 * t + 3];
    int tsum = v0 + v1 + v2 + v3;
    int lane = t & 63, w = t >> 6;
    int s = tsum;
#pragma unroll
    for (int off = 1; off < 64; off <<= 1) {
        int o = __shfl_up(s, off);
        if (lane >= off) s += o;
    }
    if (lane == 63) wsum[w] = s;
    __syncthreads();
    int wofs = 0;
#pragma unroll
    for (int k = 0; k < 4; ++k)
        if (k < w) wofs += wsum[k];
    int ex = wofs + s - tsum;
    cur[4 * t] = ex;
    cur[4 * t + 1] = ex + v0;
    cur[4 * t + 2] = ex + v0 + v1;
    cur[4 * t + 3] = ex + v0 + v1 + v2;
    __syncthreads();
    for (int k = t; k < nn; k += 256) offs[nb + k] = e0 + cur[k];
    __syncthreads();  // offs reads of cur[] must precede cursor atomics
    for (int e = e0 + t; e < e1; e += 256) {
        int p = ebuf[e];
        int r = atomicAdd(&cur[(p >> 19) & 1023], 1);
        srcs[e0 + r] = p & 0x7FFFF;
    }
}

// ------- message = relu(state @ W + b)  (fallback path only) ----------------
__global__ __launch_bounds__(256) void k_message(const float* __restrict__ state,
                                                 const float* __restrict__ W,
                                                 const float* __restrict__ b,
                                                 float* __restrict__ message) {
    int i = blockIdx.x * 256 + threadIdx.x;
    if (i >= N_NODES) return;
    const float4* sp = reinterpret_cast<const float4*>(state + (size_t)i * STATE);
    float4 v0 = sp[0], v1 = sp[1], v2 = sp[2], v3 = sp[3];
    float st[STATE] = {v0.x, v0.y, v0.z, v0.w, v1.x, v1.y, v1.z, v1.w,
                       v2.x, v2.y, v2.z, v2.w, v3.x, v3.y, v3.z, v3.w};
    float o[STATE];
#pragma unroll
    for (int s = 0; s < STATE; ++s) {
        float acc = b[s];
#pragma unroll
        for (int k = 0; k < STATE; ++k) acc = fmaf(st[k], W[k * STATE + s], acc);
        o[s] = fmaxf(acc, 0.f);
    }
    float4* mp = reinterpret_cast<float4*>(message + (size_t)i * STATE);
#pragma unroll
    for (int q = 0; q < 4; ++q)
        mp[q] = make_float4(o[4 * q], o[4 * q + 1], o[4 * q + 2], o[4 * q + 3]);
}

// ------- gather + update (+ optional fused next-message, final reduce) ------
// Rotating 2-edge software prefetch: rows for edges j+2,j+3 are issued before
// the adds of j,j+1 -> ~8 row-loads in flight per lane (fixes VGPR=24 full
// serialization seen in R6 disasm/counters).
__global__ __launch_bounds__(256) void k_gather_fused(
    const float* __restrict__ msg_in, const int* __restrict__ offs,
    const int* __restrict__ srcs, const float* __restrict__ uW,
    const float* __restrict__ ub, const float* __restrict__ mW,
    const float* __restrict__ mb, float* __restrict__ msg_out,
    const int* __restrict__ batch, const float* __restrict__ oW,
    float* __restrict__ out, float* __restrict__ state) {
    int i = blockIdx.x * 256 + threadIdx.x;
    bool valid = (i < N_NODES);
    float st[STATE];
    if (valid) {
        int start = offs[i], end = offs[i + 1];
        const float4* mv = reinterpret_cast<const float4*>(msg_in);
        float4 acc0 = make_float4(0.f, 0.f, 0.f, 0.f);
        float4 acc1 = acc0, acc2 = acc0, acc3 = acc0;
        int j = start;
        int sa = (j < end) ? srcs[j] : 0;
        int sb = (j + 1 < end) ? srcs[j + 1] : 0;
        float4 xa0 = mv[4 * (size_t)sa],     xa1 = mv[4 * (size_t)sa + 1],
               xa2 = mv[4 * (size_t)sa + 2], xa3 = mv[4 * (size_t)sa + 3];
        float4 xb0 = mv[4 * (size_t)sb],     xb1 = mv[4 * (size_t)sb + 1],
               xb2 = mv[4 * (size_t)sb + 2], xb3 = mv[4 * (size_t)sb + 3];
        while (j < end) {
            int nj = j + 2;
            int ta = (nj < end) ? srcs[nj] : 0;
            int tb = (nj + 1 < end) ? srcs[nj + 1] : 0;
            float4 ya0 = mv[4 * (size_t)ta],     ya1 = mv[4 * (size_t)ta + 1],
                   ya2 = mv[4 * (size_t)ta + 2], ya3 = mv[4 * (size_t)ta + 3];
            float4 yb0 = mv[4 * (size_t)tb],     yb1 = mv[4 * (size_t)tb + 1],
                   yb2 = mv[4 * (size_t)tb + 2], yb3 = mv[4 * (size_t)tb + 3];
            acc0 = f4add(acc0, xa0); acc1 = f4add(acc1, xa1);
            acc2 = f4add(acc2, xa2); acc3 = f4add(acc3, xa3);
            if (j + 1 < end) {
                acc0 = f4add(acc0, xb0); acc1 = f4add(acc1, xb1);
                acc2 = f4add(acc2, xb2); acc3 = f4add(acc3, xb3);
            }
            xa0 = ya0; xa1 = ya1; xa2 = ya2; xa3 = ya3;
            xb0 = yb0; xb1 = yb1; xb2 = yb2; xb3 = yb3;
            j = nj;
        }
        float ag[STATE] = {acc0.x, acc0.y, acc0.z, acc0.w,
                           acc1.x, acc1.y, acc1.z, acc1.w,
                           acc2.x, acc2.y, acc2.z, acc2.w,
                           acc3.x, acc3.y, acc3.z, acc3.w};
        float4* spv = reinterpret_cast<float4*>(state + (size_t)i * STATE);
        float4 s0 = spv[0], s1 = spv[1], s2 = spv[2], s3 = spv[3];
        st[0] = s0.x;  st[1] = s0.y;  st[2] = s0.z;  st[3] = s0.w;
        st[4] = s1.x;  st[5] = s1.y;  st[6] = s1.z;  st[7] = s1.w;
        st[8] = s2.x;  st[9] = s2.y;  st[10] = s2.z; st[11] = s2.w;
        st[12] = s3.x; st[13] = s3.y; st[14] = s3.z; st[15] = s3.w;
#pragma unroll
        for (int s = 0; s < STATE; ++s) {
            float a = ub[s];
#pragma unroll
            for (int k = 0; k < STATE; ++k) a = fmaf(ag[k], uW[k * STATE + s], a);
            st[s] += fmaxf(a, 0.f);
        }
#pragma unroll
        for (int q = 0; q < 4; ++q)
            spv[q] = make_float4(st[4 * q], st[4 * q + 1], st[4 * q + 2], st[4 * q + 3]);
        if (mW) {  // fused next-round message from this node's new state
            float mo[STATE];
#pragma unroll
            for (int s = 0; s < STATE; ++s) {
                float a = mb[s];
#pragma unroll
                for (int k = 0; k < STATE; ++k) a = fmaf(st[k], mW[k * STATE + s], a);
                mo[s] = fmaxf(a, 0.f);
            }
            float4* mp = reinterpret_cast<float4*>(msg_out + (size_t)i * STATE);
#pragma unroll
            for (int q = 0; q < 4; ++q)
                mp[q] = make_float4(mo[4 * q], mo[4 * q + 1], mo[4 * q + 2], mo[4 * q + 3]);
        }
    }
    if (oW) {  // final round: fused graph reduction (batch sorted)
        int lane = threadIdx.x & 63;
        float v = 0.f;
        int bg = -1;
        if (valid) {
            bg = batch[i];
#pragma unroll
            for (int k = 0; k < STATE; ++k) v = fmaf(st[k], oW[k], v);
        }
#pragma unroll
        for (int off = 1; off < 64; off <<= 1) {
            float ov = __shfl_up(v, off);
            int ob = __shfl_up(bg, off);
            if (lane >= off && ob == bg) v += ov;
        }
        int nb = __shfl_down(bg, 1);
        if (valid && (lane == 63 || nb != bg)) unsafeAtomicAdd(&out[bg], v);
    }
}

// ------------- out[g] = out_b -----------------------------------------------
__global__ __launch_bounds__(256) void k_out_init(const float* __restrict__ out_b,
                                                  float* __restrict__ out) {
    int g = blockIdx.x * 256 + threadIdx.x;
    if (g < N_GRAPHS) out[g] = out_b[0];
}

// ------------- fallback reduce (non-fused path) -----------------------------
__global__ __launch_bounds__(256) void k_reduce(const float* __restrict__ state,
                                                const int* __restrict__ batch,
                                                const float* __restrict__ out_W,
                                                float* __restrict__ out) {
    int i = blockIdx.x * 256 + threadIdx.x;
    int lane = threadIdx.x & 63;
    bool valid = (i < N_NODES);
    float v = 0.f;
    int bg = -1;
    if (valid) {
        bg = batch[i];
        const float4* sp = reinterpret_cast<const float4*>(state + (size_t)i * STATE);
        float4 s0 = sp[0], s1 = sp[1], s2 = sp[2], s3 = sp[3];
        float st[STATE] = {s0.x, s0.y, s0.z, s0.w, s1.x, s1.y, s1.z, s1.w,
                           s2.x, s2.y, s2.z, s2.w, s3.x, s3.y, s3.z, s3.w};
        float acc = 0.f;
#pragma unroll
        for (int k = 0; k < STATE; ++k) acc = fmaf(st[k], out_W[k], acc);
        v = acc;
    }
#pragma unroll
    for (int off = 1; off < 64; off <<= 1) {
        float ov = __shfl_up(v, off);
        int ob = __shfl_up(bg, off);
        if (lane >= off && ob == bg) v += ov;
    }
    int nb = __shfl_down(bg, 1);
    if (valid && (lane == 63 || nb != bg)) unsafeAtomicAdd(&out[bg], v);
}

extern "C" void kernel_launch(void* const* d_in, const int* in_sizes, int n_in,
                              void* d_out, int out_size, void* d_ws, size_t ws_size,
                              hipStream_t stream) {
    const float* x     = (const float*)d_in[0];
    const int*   ei    = (const int*)d_in[1];
    const int*   batch = (const int*)d_in[2];
    const float* in_W  = (const float*)d_in[3];
    const float* in_b  = (const float*)d_in[4];
    const float* msg_W = (const float*)d_in[5];
    const float* msg_b = (const float*)d_in[6];
    const float* upd_W = (const float*)d_in[7];
    const float* upd_b = (const float*)d_in[8];
    const float* out_W = (const float*)d_in[9];
    const float* out_b = (const float*)d_in[10];
    float* out = (float*)d_out;

    const size_t NF = (size_t)N_NODES * STATE;
    float* state = (float*)d_ws;                       // 32 MB
    float* msgA  = state + NF;                         // 32 MB
    int*   srcs  = (int*)(msgA + NF);                  // 20 MB
    int*   offs  = srcs + N_EDGES;                     // 2 MB (+1)
    int*   bcnt  = offs + N_NODES + 1;                 // 489
    int*   boffs = bcnt + NBUCK;                       // 490
    int*   bb    = boffs + NBUCK + 1;                  // 1 MB
    float* msgB  = (float*)(bb + (size_t)NBLK1 * NBUCK);  // 32 MB (fused only)
    size_t need  = (size_t)((char*)(msgB + NF) - (char*)d_ws);
    bool   fused = ws_size >= need;
    int*   ebuf  = (int*)d_ws;  // overlaps state; dead before k_input

    const int nbN = (N_NODES + 255) / 256;
    const int nbG = (N_GRAPHS + 255) / 256;

    // ---- CSR build by dst (bucketed, near-atomic-free) ----
    k_zero<<<(NBUCK + 255) / 256, 256, 0, stream>>>(bcnt, NBUCK);
    k_bhist<<<NBLK1, 256, 0, stream>>>(ei, bcnt, bb);
    k_bscan<<<1, 256, 0, stream>>>(bcnt, boffs, offs);
    k_bscatter<<<NBLK1, 256, 0, stream>>>(ei, boffs, bb, ebuf);
    k_bcsr<<<NBUCK, 256, 0, stream>>>(ebuf, boffs, offs, srcs);

    // ---- GNN ----
    k_input<<<nbN, 256, 0, stream>>>(x, in_W, in_b, msg_W, msg_b, state, msgA);
    k_out_init<<<nbG, 256, 0, stream>>>(out_b, out);
    if (fused) {
        float* mi = msgA;
        float* mo = msgB;
        for (int r = 0; r < 4; ++r) {
            bool last = (r == 3);
            k_gather_fused<<<nbN, 256, 0, stream>>>(
                mi, offs, srcs, upd_W + r * STATE * STATE, upd_b + r * STATE,
                last ? nullptr : msg_W + (r + 1) * STATE * STATE,
                last ? nullptr : msg_b + (r + 1) * STATE,
                last ? nullptr : mo,
                last ? batch : nullptr, last ? out_W : nullptr,
                last ? out : nullptr, state);
            float* t = mi; mi = mo; mo = t;
        }
    } else {
        for (int r = 0; r < 4; ++r) {
            k_gather_fused<<<nbN, 256, 0, stream>>>(
                msgA, offs, srcs, upd_W + r * STATE * STATE, upd_b + r * STATE,
                nullptr, nullptr, nullptr, nullptr, nullptr, nullptr, state);
            if (r < 3)
                k_message<<<nbN, 256, 0, stream>>>(state,
                                                   msg_W + (r + 1) * STATE * STATE,
                                                   msg_b + (r + 1) * STATE, msgA);
        }
        k_reduce<<<nbN, 256, 0, stream>>>(state, batch, out_W, out);
    }
}

// Round 12
// 677.265 us; speedup vs baseline: 1.2200x; 1.2148x over previous
//
#include <hip/hip_runtime.h>
#include <hip/hip_fp16.h>

#define N_NODES 500000
#define N_EDGES 5000000
#define N_GRAPHS 5000
#define FEAT 7
#define STATE 16
#define NBUCK ((N_NODES + 1023) >> 10)   // 489 buckets of 1024 nodes
#define NBLK1 512
#define EPB ((N_EDGES + NBLK1 - 1) / NBLK1)  // 9766 edges per pass-1 block

// unpack 8 halves (one float4) and add into 4 float2 accumulators
__device__ __forceinline__ void addrow8(float4 v, float2* acc) {
    const __half2* h = reinterpret_cast<const __half2*>(&v);
#pragma unroll
    for (int k = 0; k < 4; ++k) {
        float2 f = __half22float2(h[k]);
        acc[k].x += f.x;
        acc[k].y += f.y;
    }
}
// pack 8 floats into one float4 of halves
__device__ __forceinline__ float4 pack8(const float* v) {
    float4 r;
    __half2* h = reinterpret_cast<__half2*>(&r);
#pragma unroll
    for (int k = 0; k < 4; ++k) h[k] = __floats2half2_rn(v[2 * k], v[2 * k + 1]);
    return r;
}

// ---------------- zero an int buffer ----------------------------------------
__global__ __launch_bounds__(256) void k_zero(int* __restrict__ p, int n) {
    int i = blockIdx.x * 256 + threadIdx.x;
    if (i < n) p[i] = 0;
}

// ------ input layer + round-0 message (fp16), fused -------------------------
__global__ __launch_bounds__(256) void k_input(const float* __restrict__ x,
                                               const float* __restrict__ W,
                                               const float* __restrict__ b,
                                               const float* __restrict__ mW,
                                               const float* __restrict__ mb,
                                               float* __restrict__ state,
                                               float* __restrict__ message) {
    int i = blockIdx.x * 256 + threadIdx.x;
    if (i >= N_NODES) return;
    float xi[FEAT];
#pragma unroll
    for (int f = 0; f < FEAT; ++f) xi[f] = x[(size_t)i * FEAT + f];
    float o[STATE];
#pragma unroll
    for (int s = 0; s < STATE; ++s) {
        float acc = b[s];
#pragma unroll
        for (int f = 0; f < FEAT; ++f) acc = fmaf(xi[f], W[f * STATE + s], acc);
        o[s] = fmaxf(acc, 0.f);
    }
    float4* dst = reinterpret_cast<float4*>(state + (size_t)i * STATE);
#pragma unroll
    for (int q = 0; q < 4; ++q)
        dst[q] = make_float4(o[4 * q], o[4 * q + 1], o[4 * q + 2], o[4 * q + 3]);
    float mo[STATE];
#pragma unroll
    for (int s = 0; s < STATE; ++s) {
        float acc = mb[s];
#pragma unroll
        for (int k = 0; k < STATE; ++k) acc = fmaf(o[k], mW[k * STATE + s], acc);
        mo[s] = fmaxf(acc, 0.f);
    }
    float4* mp = reinterpret_cast<float4*>(message) + 2 * (size_t)i;  // 32B row
    mp[0] = pack8(mo);
    mp[1] = pack8(mo + 8);
}

// ---- CSR pass 1a: per-block bucket histogram + global base capture ---------
__global__ __launch_bounds__(256) void k_bhist(const int* __restrict__ ei,
                                               int* __restrict__ bcnt,
                                               int* __restrict__ bb) {
    __shared__ int bins[NBUCK];
    int t = threadIdx.x, blk = blockIdx.x;
    for (int k = t; k < NBUCK; k += 256) bins[k] = 0;
    __syncthreads();
    int e0 = blk * EPB, e1 = min(e0 + EPB, N_EDGES);
    for (int e = e0 + t; e < e1; e += 256) {
        int d = ei[N_EDGES + e];
        atomicAdd(&bins[d >> 10], 1);
    }
    __syncthreads();
    for (int k = t; k < NBUCK; k += 256)
        bb[blk * NBUCK + k] = atomicAdd(&bcnt[k], bins[k]);
}

// ---- CSR pass 1b: tiny exclusive scan of bucket counts ---------------------
__global__ __launch_bounds__(256) void k_bscan(const int* __restrict__ bcnt,
                                               int* __restrict__ boffs,
                                               int* __restrict__ offs) {
    __shared__ int sc[NBUCK];
    int t = threadIdx.x;
    for (int k = t; k < NBUCK; k += 256) sc[k] = bcnt[k];
    __syncthreads();
    if (t == 0) {
        int run = 0;
        for (int k = 0; k < NBUCK; ++k) { int v = sc[k]; sc[k] = run; run += v; }
    }
    __syncthreads();
    for (int k = t; k < NBUCK; k += 256) boffs[k] = sc[k];
    if (t == 0) { boffs[NBUCK] = N_EDGES; offs[N_NODES] = N_EDGES; }
}

// ---- CSR pass 1c: partition edges into bucket-contiguous packed storage ----
// pack = src | (dst&1023)<<19   (valid: N_NODES < 2^19)
__global__ __launch_bounds__(256) void k_bscatter(const int* __restrict__ ei,
                                                  const int* __restrict__ boffs,
                                                  const int* __restrict__ bb,
                                                  int* __restrict__ ebuf) {
    __shared__ int cur[NBUCK];
    int t = threadIdx.x, blk = blockIdx.x;
    for (int k = t; k < NBUCK; k += 256) cur[k] = 0;
    __syncthreads();
    int e0 = blk * EPB, e1 = min(e0 + EPB, N_EDGES);
    for (int e = e0 + t; e < e1; e += 256) {
        int s = ei[e];
        int d = ei[N_EDGES + e];
        int bin = d >> 10;
        int r = atomicAdd(&cur[bin], 1);
        ebuf[boffs[bin] + bb[blk * NBUCK + bin] + r] = s | ((d & 1023) << 19);
    }
}

// ---- CSR pass 2: per-bucket CSR build fully in LDS (no global atomics) -----
__global__ __launch_bounds__(256) void k_bcsr(const int* __restrict__ ebuf,
                                              const int* __restrict__ boffs,
                                              int* __restrict__ offs,
                                              int* __restrict__ srcs) {
    __shared__ int hist[1024];
    __shared__ int cur[1024];
    __shared__ int wsum[4];
    int t = threadIdx.x, blk = blockIdx.x;
    int nb = blk << 10;
    int nn = min(1024, N_NODES - nb);
    for (int k = t; k < 1024; k += 256) hist[k] = 0;
    __syncthreads();
    int e0 = boffs[blk], e1 = boffs[blk + 1];
    for (int e = e0 + t; e < e1; e += 256)
        atomicAdd(&hist[(ebuf[e] >> 19) & 1023], 1);
    __syncthreads();
    int v0 = hist[4 * t], v1 = hist[4 * t + 1], v2 = hist[4 * t + 2], v3 = hist[4 * t + 3];
    int tsum = v0 + v1 + v2 + v3;
    int lane = t & 63, w = t >> 6;
    int s = tsum;
#pragma unroll
    for (int off = 1; off < 64; off <<= 1) {
        int o = __shfl_up(s, off);
        if (lane >= off) s += o;
    }
    if (lane == 63) wsum[w] = s;
    __syncthreads();
    int wofs = 0;
#pragma unroll
    for (int k = 0; k < 4; ++k)
        if (k < w) wofs += wsum[k];
    int ex = wofs + s - tsum;
    cur[4 * t] = ex;
    cur[4 * t + 1] = ex + v0;
    cur[4 * t + 2] = ex + v0 + v1;
    cur[4 * t + 3] = ex + v0 + v1 + v2;
    __syncthreads();
    for (int k = t; k < nn; k += 256) offs[nb + k] = e0 + cur[k];
    __syncthreads();  // offs reads of cur[] must precede cursor atomics
    for (int e = e0 + t; e < e1; e += 256) {
        int p = ebuf[e];
        int r = atomicAdd(&cur[(p >> 19) & 1023], 1);
        srcs[e0 + r] = p & 0x7FFFF;
    }
}

// ------- message = relu(state @ W + b) -> fp16 (fallback path only) ---------
__global__ __launch_bounds__(256) void k_message(const float* __restrict__ state,
                                                 const float* __restrict__ W,
                                                 const float* __restrict__ b,
                                                 float* __restrict__ message) {
    int i = blockIdx.x * 256 + threadIdx.x;
    if (i >= N_NODES) return;
    const float4* sp = reinterpret_cast<const float4*>(state + (size_t)i * STATE);
    float4 v0 = sp[0], v1 = sp[1], v2 = sp[2], v3 = sp[3];
    float st[STATE] = {v0.x, v0.y, v0.z, v0.w, v1.x, v1.y, v1.z, v1.w,
                       v2.x, v2.y, v2.z, v2.w, v3.x, v3.y, v3.z, v3.w};
    float o[STATE];
#pragma unroll
    for (int s = 0; s < STATE; ++s) {
        float acc = b[s];
#pragma unroll
        for (int k = 0; k < STATE; ++k) acc = fmaf(st[k], W[k * STATE + s], acc);
        o[s] = fmaxf(acc, 0.f);
    }
    float4* mp = reinterpret_cast<float4*>(message) + 2 * (size_t)i;
    mp[0] = pack8(o);
    mp[1] = pack8(o + 8);
}

// ------- gather(fp16) + update (+ fused next-message, final reduce) ---------
// 2-row rotating prefetch; each row is 32B (2x float4 of halves).
__global__ __launch_bounds__(256) void k_gather_fused(
    const float* __restrict__ msg_in, const int* __restrict__ offs,
    const int* __restrict__ srcs, const float* __restrict__ uW,
    const float* __restrict__ ub, const float* __restrict__ mW,
    const float* __restrict__ mb, float* __restrict__ msg_out,
    const int* __restrict__ batch, const float* __restrict__ oW,
    float* __restrict__ out, float* __restrict__ state) {
    int i = blockIdx.x * 256 + threadIdx.x;
    bool valid = (i < N_NODES);
    float st[STATE];
    if (valid) {
        int start = offs[i], end = offs[i + 1];
        const float4* mv = reinterpret_cast<const float4*>(msg_in);
        float2 acc[8];
#pragma unroll
        for (int k = 0; k < 8; ++k) acc[k] = make_float2(0.f, 0.f);
        int j = start;
        int sa = (j < end) ? srcs[j] : 0;
        int sb = (j + 1 < end) ? srcs[j + 1] : 0;
        float4 xa0 = mv[2 * (size_t)sa], xa1 = mv[2 * (size_t)sa + 1];
        float4 xb0 = mv[2 * (size_t)sb], xb1 = mv[2 * (size_t)sb + 1];
        while (j < end) {
            int nj = j + 2;
            int ta = (nj < end) ? srcs[nj] : 0;
            int tb = (nj + 1 < end) ? srcs[nj + 1] : 0;
            float4 ya0 = mv[2 * (size_t)ta], ya1 = mv[2 * (size_t)ta + 1];
            float4 yb0 = mv[2 * (size_t)tb], yb1 = mv[2 * (size_t)tb + 1];
            addrow8(xa0, acc);
            addrow8(xa1, acc + 4);
            if (j + 1 < end) {
                addrow8(xb0, acc);
                addrow8(xb1, acc + 4);
            }
            xa0 = ya0; xa1 = ya1;
            xb0 = yb0; xb1 = yb1;
            j = nj;
        }
        float ag[STATE] = {acc[0].x, acc[0].y, acc[1].x, acc[1].y,
                           acc[2].x, acc[2].y, acc[3].x, acc[3].y,
                           acc[4].x, acc[4].y, acc[5].x, acc[5].y,
                           acc[6].x, acc[6].y, acc[7].x, acc[7].y};
        float4* spv = reinterpret_cast<float4*>(state + (size_t)i * STATE);
        float4 s0 = spv[0], s1 = spv[1], s2 = spv[2], s3 = spv[3];
        st[0] = s0.x;  st[1] = s0.y;  st[2] = s0.z;  st[3] = s0.w;
        st[4] = s1.x;  st[5] = s1.y;  st[6] = s1.z;  st[7] = s1.w;
        st[8] = s2.x;  st[9] = s2.y;  st[10] = s2.z; st[11] = s2.w;
        st[12] = s3.x; st[13] = s3.y; st[14] = s3.z; st[15] = s3.w;
#pragma unroll
        for (int s = 0; s < STATE; ++s) {
            float a = ub[s];
#pragma unroll
            for (int k = 0; k < STATE; ++k) a = fmaf(ag[k], uW[k * STATE + s], a);
            st[s] += fmaxf(a, 0.f);
        }
#pragma unroll
        for (int q = 0; q < 4; ++q)
            spv[q] = make_float4(st[4 * q], st[4 * q + 1], st[4 * q + 2], st[4 * q + 3]);
        if (mW) {  // fused next-round message (fp16) from this node's new state
            float mo[STATE];
#pragma unroll
            for (int s = 0; s < STATE; ++s) {
                float a = mb[s];
#pragma unroll
                for (int k = 0; k < STATE; ++k) a = fmaf(st[k], mW[k * STATE + s], a);
                mo[s] = fmaxf(a, 0.f);
            }
            float4* mp = reinterpret_cast<float4*>(msg_out) + 2 * (size_t)i;
            mp[0] = pack8(mo);
            mp[1] = pack8(mo + 8);
        }
    }
    if (oW) {  // final round: fused graph reduction (batch sorted)
        int lane = threadIdx.x & 63;
        float v = 0.f;
        int bg = -1;
        if (valid) {
            bg = batch[i];
#pragma unroll
            for (int k = 0; k < STATE; ++k) v = fmaf(st[k], oW[k], v);
        }
#pragma unroll
        for (int off = 1; off < 64; off <<= 1) {
            float ov = __shfl_up(v, off);
            int ob = __shfl_up(bg, off);
            if (lane >= off && ob == bg) v += ov;
        }
        int nb = __shfl_down(bg, 1);
        if (valid && (lane == 63 || nb != bg)) unsafeAtomicAdd(&out[bg], v);
    }
}

// ------------- out[g] = out_b -----------------------------------------------
__global__ __launch_bounds__(256) void k_out_init(const float* __restrict__ out_b,
                                                  float* __restrict__ out) {
    int g = blockIdx.x * 256 + threadIdx.x;
    if (g < N_GRAPHS) out[g] = out_b[0];
}

// ------------- fallback reduce (non-fused path) -----------------------------
__global__ __launch_bounds__(256) void k_reduce(const float* __restrict__ state,
                                                const int* __restrict__ batch,
                                                const float* __restrict__ out_W,
                                                float* __restrict__ out) {
    int i = blockIdx.x * 256 + threadIdx.x;
    int lane = threadIdx.x & 63;
    bool valid = (i < N_NODES);
    float v = 0.f;
    int bg = -1;
    if (valid) {
        bg = batch[i];
        const float4* sp = reinterpret_cast<const float4*>(state + (size_t)i * STATE);
        float4 s0 = sp[0], s1 = sp[1], s2 = sp[2], s3 = sp[3];
        float st[STATE] = {s0.x, s0.y, s0.z, s0.w, s1.x, s1.y, s1.z, s1.w,
                           s2.x, s2.y, s2.z, s2.w, s3.x, s3.y, s3.z, s3.w};
        float acc = 0.f;
#pragma unroll
        for (int k = 0; k < STATE; ++k) acc = fmaf(st[k], out_W[k], acc);
        v = acc;
    }
#pragma unroll
    for (int off = 1; off < 64; off <<= 1) {
        float ov = __shfl_up(v, off);
        int ob = __shfl_up(bg, off);
        if (lane >= off && ob == bg) v += ov;
    }
    int nb = __shfl_down(bg, 1);
    if (valid && (lane == 63 || nb != bg)) unsafeAtomicAdd(&out[bg], v);
}

extern "C" void kernel_launch(void* const* d_in, const int* in_sizes, int n_in,
                              void* d_out, int out_size, void* d_ws, size_t ws_size,
                              hipStream_t stream) {
    const float* x     = (const float*)d_in[0];
    const int*   ei    = (const int*)d_in[1];
    const int*   batch = (const int*)d_in[2];
    const float* in_W  = (const float*)d_in[3];
    const float* in_b  = (const float*)d_in[4];
    const float* msg_W = (const float*)d_in[5];
    const float* msg_b = (const float*)d_in[6];
    const float* upd_W = (const float*)d_in[7];
    const float* upd_b = (const float*)d_in[8];
    const float* out_W = (const float*)d_in[9];
    const float* out_b = (const float*)d_in[10];
    float* out = (float*)d_out;

    const size_t NF = (size_t)N_NODES * STATE;
    // layout (~87 MB): state fp32, msgA/msgB fp16 (16 MB each)
    float* state = (float*)d_ws;                          // 32 MB
    float* msgA  = state + NF;                            // 16 MB (fp16 rows)
    float* msgB  = (float*)((char*)msgA + NF * 2);        // 16 MB (fp16 rows)
    int*   srcs  = (int*)((char*)msgB + NF * 2);          // 20 MB
    int*   offs  = srcs + N_EDGES;                        // 2 MB (+1)
    int*   bcnt  = offs + N_NODES + 1;                    // 489
    int*   boffs = bcnt + NBUCK;                          // 490
    int*   bb    = boffs + NBUCK + 1;                     // 1 MB
    size_t need  = (size_t)((char*)(bb + (size_t)NBLK1 * NBUCK) - (char*)d_ws);
    bool   fused = ws_size >= need;
    int*   ebuf  = (int*)d_ws;  // overlaps state; dead before k_input

    const int nbN = (N_NODES + 255) / 256;
    const int nbG = (N_GRAPHS + 255) / 256;

    // ---- CSR build by dst (bucketed, near-atomic-free) ----
    k_zero<<<(NBUCK + 255) / 256, 256, 0, stream>>>(bcnt, NBUCK);
    k_bhist<<<NBLK1, 256, 0, stream>>>(ei, bcnt, bb);
    k_bscan<<<1, 256, 0, stream>>>(bcnt, boffs, offs);
    k_bscatter<<<NBLK1, 256, 0, stream>>>(ei, boffs, bb, ebuf);
    k_bcsr<<<NBUCK, 256, 0, stream>>>(ebuf, boffs, offs, srcs);

    // ---- GNN ----
    k_input<<<nbN, 256, 0, stream>>>(x, in_W, in_b, msg_W, msg_b, state, msgA);
    k_out_init<<<nbG, 256, 0, stream>>>(out_b, out);
    if (fused) {
        float* mi = msgA;
        float* mo = msgB;
        for (int r = 0; r < 4; ++r) {
            bool last = (r == 3);
            k_gather_fused<<<nbN, 256, 0, stream>>>(
                mi, offs, srcs, upd_W + r * STATE * STATE, upd_b + r * STATE,
                last ? nullptr : msg_W + (r + 1) * STATE * STATE,
                last ? nullptr : msg_b + (r + 1) * STATE,
                last ? nullptr : mo,
                last ? batch : nullptr, last ? out_W : nullptr,
                last ? out : nullptr, state);
            float* t = mi; mi = mo; mo = t;
        }
    } else {
        for (int r = 0; r < 4; ++r) {
            k_gather_fused<<<nbN, 256, 0, stream>>>(
                msgA, offs, srcs, upd_W + r * STATE * STATE, upd_b + r * STATE,
                nullptr, nullptr, nullptr, nullptr, nullptr, nullptr, state);
            if (r < 3)
                k_message<<<nbN, 256, 0, stream>>>(state,
                                                   msg_W + (r + 1) * STATE * STATE,
                                                   msg_b + (r + 1) * STATE, msgA);
        }
        k_reduce<<<nbN, 256, 0, stream>>>(state, batch, out_W, out);
    }
}